// Round 15
// baseline (357.096 us; speedup 1.0000x reference)
//
#include <hip/hip_runtime.h>

// Problem constants
#define B_  2
#define S_  4096
#define D_  1024
#define H_  8
#define DK_ 128
#define DV_ 128
#define SEG_ 512
#define NSEG_ 8
#define BH_ 16
#define M_ 8192          // B*S

typedef __attribute__((ext_vector_type(8))) short bf16x8;
typedef __attribute__((ext_vector_type(4))) float f32x4;

__device__ __forceinline__ float elu1(float x) { return x > 0.f ? x + 1.f : __expf(x); }
__device__ __forceinline__ float sigmoidf(float x) { return 1.f / (1.f + __expf(-x)); }

__device__ __forceinline__ unsigned short f2b(float f) {  // RNE fp32->bf16
    union { float f; unsigned int u; } x; x.f = f;
    unsigned int r = x.u + 0x7fffu + ((x.u >> 16) & 1u);
    return (unsigned short)(r >> 16);
}
__device__ __forceinline__ float b2f(unsigned short u) {
    union { unsigned int u; float f; } x; x.u = ((unsigned int)u) << 16; return x.f;
}

__device__ __forceinline__ void gl2lds16(const void* g, void* l) {
    __builtin_amdgcn_global_load_lds(
        (const __attribute__((address_space(1))) void*)g,
        (__attribute__((address_space(3))) void*)l, 16, 0, 0);
}

// ---------------------------------------------------------------------------
// fp32 -> bf16 row-major convert
// ---------------------------------------------------------------------------
__global__ __launch_bounds__(256) void conv_bf16(
    const float* __restrict__ src, unsigned short* __restrict__ dst)
{
    int i = (blockIdx.x * 256 + threadIdx.x) * 4;
    float4 v = *(const float4*)(src + i);
    ushort4 o;
    o.x = f2b(v.x); o.y = f2b(v.y); o.z = f2b(v.z); o.w = f2b(v.w);
    *(ushort4*)(dst + i) = o;
}

// ---------------------------------------------------------------------------
// fp32 (R x C) -> bf16 transposed (C x R). blockIdx.z = matrix index.
// ---------------------------------------------------------------------------
__global__ __launch_bounds__(256) void transpose_conv(
    const float* __restrict__ src, unsigned short* __restrict__ dst, int R, int C)
{
    __shared__ float tile[32][33];
    const size_t moff = (size_t)blockIdx.z * R * C;
    src += moff; dst += moff;
    const int c0 = blockIdx.x * 32, r0 = blockIdx.y * 32;
    const int tx = threadIdx.x & 31, ty = threadIdx.x >> 5;   // 32 x 8
    #pragma unroll
    for (int i = 0; i < 32; i += 8)
        tile[ty + i][tx] = src[(size_t)(r0 + ty + i) * C + c0 + tx];
    __syncthreads();
    #pragma unroll
    for (int i = 0; i < 32; i += 8)
        dst[(size_t)(c0 + ty + i) * R + r0 + tx] = f2b(tile[tx][ty + i]);
}

// ---------------------------------------------------------------------------
// Fused Wk/Wv/Wq transpose: 24 matrices (1024x128 each) in one launch.
// ---------------------------------------------------------------------------
__global__ __launch_bounds__(256) void transpose_conv3(
    const float* __restrict__ Wk, const float* __restrict__ Wv,
    const float* __restrict__ Wq, unsigned short* __restrict__ dst)
{
    __shared__ float tile[32][33];
    const int z = blockIdx.z;
    const int w = z >> 3;
    const float* src = (w == 0) ? Wk : (w == 1) ? Wv : Wq;
    src += (size_t)(z & 7) * 131072;
    dst += (size_t)z * 131072;
    const int c0 = blockIdx.x * 32, r0 = blockIdx.y * 32;
    const int tx = threadIdx.x & 31, ty = threadIdx.x >> 5;   // 32 x 8
    #pragma unroll
    for (int i = 0; i < 32; i += 8)
        tile[ty + i][tx] = src[(size_t)(r0 + ty + i) * 128 + c0 + tx];
    __syncthreads();
    #pragma unroll
    for (int i = 0; i < 32; i += 8)
        dst[(size_t)(c0 + ty + i) * 1024 + r0 + tx] = f2b(tile[tx][ty + i]);
}

// ---------------------------------------------------------------------------
// colsum[bh*8+seg][dk] = sum_{s in seg} elu1(K[s][dk])
// ---------------------------------------------------------------------------
__global__ __launch_bounds__(256) void colsum_k(
    const unsigned short* __restrict__ Kbb, float* __restrict__ colsum)
{
    __shared__ float red[32][128];
    const int t = threadIdx.x;
    const int bh = blockIdx.x >> 3, seg = blockIdx.x & 7;
    const unsigned short* Kp = Kbb + ((size_t)bh * 4096 + seg * 512) * 128;
    const int rbase = t >> 3, c0 = (t & 7) * 16;
    float part[16] = {};
    for (int chunk = 0; chunk < 16; ++chunk) {
        const unsigned short* p = Kp + (size_t)(chunk * 32 + rbase) * 128 + c0;
        bf16x8 a = *(const bf16x8*)p;
        bf16x8 b = *(const bf16x8*)(p + 8);
        #pragma unroll
        for (int j = 0; j < 8; ++j) {
            part[j]     += elu1(b2f((unsigned short)a[j]));
            part[j + 8] += elu1(b2f((unsigned short)b[j]));
        }
    }
    #pragma unroll
    for (int j = 0; j < 16; ++j) red[rbase][c0 + j] = part[j];
    __syncthreads();
    if (t < 128) {
        float s = 0.f;
        #pragma unroll
        for (int r = 0; r < 32; ++r) s += red[r][t];
        colsum[(size_t)blockIdx.x * 128 + t] = s;
    }
}

// ---------------------------------------------------------------------------
// zseg[bh*8+seg][dk] = 1/128 + prefix(colsum); den[bh][s] = sigma_k[s].zseg
// ---------------------------------------------------------------------------
__global__ __launch_bounds__(256) void den_z(
    const unsigned short* __restrict__ Kbb, const float* __restrict__ colsum,
    float* __restrict__ den, float* __restrict__ zseg)
{
    __shared__ float zs[128];
    const int t = threadIdx.x;
    const int bh = blockIdx.x >> 3, seg = blockIdx.x & 7;
    if (t < 128) {
        float z = 1.f / 128.f;
        for (int j = 0; j < seg; ++j) z += colsum[(size_t)(bh * 8 + j) * 128 + t];
        zs[t] = z;
        zseg[(size_t)blockIdx.x * 128 + t] = z;
    }
    __syncthreads();
    #pragma unroll
    for (int rr = 0; rr < 2; ++rr) {
        int s = t + rr * 256;
        const unsigned short* kp = Kbb + ((size_t)bh * 4096 + seg * 512 + s) * 128;
        float d = 0.f;
        #pragma unroll 4
        for (int f = 0; f < 16; ++f) {
            bf16x8 a = *(const bf16x8*)(kp + f * 8);
            #pragma unroll
            for (int j = 0; j < 8; ++j)
                d += elu1(b2f((unsigned short)a[j])) * zs[f * 8 + j];
        }
        den[(size_t)bh * 4096 + seg * 512 + s] = d;
    }
}

// ---------------------------------------------------------------------------
// SkT[bh][dk][s] = elu1(K[s][dk]); SkTs = SkT / den[s]
// ---------------------------------------------------------------------------
__global__ __launch_bounds__(256) void sigma_kT2(
    const unsigned short* __restrict__ Kbb, const float* __restrict__ den,
    unsigned short* __restrict__ SkT, unsigned short* __restrict__ SkTs)
{
    __shared__ float tile[32][33];
    __shared__ float rden[32];
    const int bh = blockIdx.z;
    const int s0 = blockIdx.x * 32, dk0 = blockIdx.y * 32;
    const int tx = threadIdx.x & 31, ty = threadIdx.x >> 5;   // 32 x 8
    if (threadIdx.x < 32) rden[threadIdx.x] = 1.f / den[(size_t)bh * 4096 + s0 + threadIdx.x];
    #pragma unroll
    for (int i = 0; i < 32; i += 8)
        tile[ty + i][tx] = elu1(b2f(Kbb[((size_t)bh * 4096 + s0 + ty + i) * 128 + dk0 + tx]));
    __syncthreads();
    #pragma unroll
    for (int i = 0; i < 32; i += 8) {
        float v = tile[tx][ty + i];
        size_t o = ((size_t)bh * 128 + dk0 + ty + i) * 4096 + s0 + tx;
        SkT[o]  = f2b(v);
        SkTs[o] = f2b(v * rden[tx]);
    }
}

// ---------------------------------------------------------------------------
// 128x128 bf16 MFMA core (4 waves), 3-buffer 2-deep counted-vmcnt (proven).
// ---------------------------------------------------------------------------
__device__ __forceinline__ void mfma_gemm_128(
    const unsigned short* __restrict__ A, int lda,
    const unsigned short* __restrict__ Bt, int ldb, int K,
    unsigned short* As, unsigned short* Bs, f32x4 acc[4][4])
{
    const int tid = threadIdx.x;
    const int wave = tid >> 6, lane = tid & 63;
    const int r4 = lane >> 2;
    const int c4s = (((lane & 3) ^ ((lane >> 2) & 3)) * 8);   // swizzled source chunk
    const int lrow = lane & 15, lquad = lane >> 4;
    const int sl8 = (lquad ^ (lrow & 3)) * 8;                 // matching read slot
    const int wm = (wave >> 1) * 64, wn = (wave & 1) * 64;
    const int ar0 = wave * 32, ar1 = wave * 32 + 16;
    const int T = K >> 5;

    auto STAGE = [&](int t, int bufidx) {
        unsigned short* Ab = As + bufidx * 4096;
        unsigned short* Bb = Bs + bufidx * 4096;
        const int kk = t * 32;
        gl2lds16(A  + (size_t)(ar0 + r4) * lda + kk + c4s, Ab + ar0 * 32);
        gl2lds16(A  + (size_t)(ar1 + r4) * lda + kk + c4s, Ab + ar1 * 32);
        gl2lds16(Bt + (size_t)(ar0 + r4) * ldb + kk + c4s, Bb + ar0 * 32);
        gl2lds16(Bt + (size_t)(ar1 + r4) * ldb + kk + c4s, Bb + ar1 * 32);
    };

    STAGE(0, 0);
    STAGE(1, 1);
    int cur = 0;
    for (int t = 0; t < T; ++t) {
        if (t + 2 < T) {
            int nb = cur + 2; if (nb >= 3) nb -= 3;
            STAGE(t + 2, nb);
            asm volatile("s_waitcnt vmcnt(8)" ::: "memory");   // tile t landed
        } else if (t + 1 < T) {
            asm volatile("s_waitcnt vmcnt(4)" ::: "memory");
        } else {
            asm volatile("s_waitcnt vmcnt(0)" ::: "memory");
        }
        __builtin_amdgcn_s_barrier();
        __builtin_amdgcn_sched_barrier(0);
        const unsigned short* Ac = As + cur * 4096;
        const unsigned short* Bc = Bs + cur * 4096;
        bf16x8 af[4], bfr[4];
        #pragma unroll
        for (int i = 0; i < 4; ++i)
            af[i] = *(const bf16x8*)(Ac + (wm + i * 16 + lrow) * 32 + sl8);
        #pragma unroll
        for (int j = 0; j < 4; ++j)
            bfr[j] = *(const bf16x8*)(Bc + (wn + j * 16 + lrow) * 32 + sl8);
        #pragma unroll
        for (int i = 0; i < 4; ++i)
            #pragma unroll
            for (int j = 0; j < 4; ++j)
                acc[i][j] = __builtin_amdgcn_mfma_f32_16x16x32_bf16(af[i], bfr[j], acc[i][j], 0, 0, 0);
        __builtin_amdgcn_s_barrier();
        __builtin_amdgcn_sched_barrier(0);
        cur += 1; if (cur >= 3) cur -= 3;
    }
}

// ---------------------------------------------------------------------------
// QKV projection: xb (8192x1024 bf16) @ Wtb[panel] (128x1024 bf16 = W^T)
// GRID TRANSPOSED: panel on x (24), m-tile on y (64). With x-fastest
// dispatch and 24 % 8 == 0, all 64 blocks of a panel land on the SAME XCD
// -> each B panel resident in exactly one L2 (panel-locality probe; pure
// index relabel, math identical).
// ---------------------------------------------------------------------------
__global__ __launch_bounds__(256) void gemm_qkv_mfma(
    const unsigned short* __restrict__ xb, const unsigned short* __restrict__ Wtb,
    unsigned short* __restrict__ Qbb, unsigned short* __restrict__ Kbb,
    unsigned short* __restrict__ Vtb)
{
    __shared__ unsigned short As[3 * 128 * 32];
    __shared__ unsigned short Bs[3 * 128 * 32];
    const int m0 = blockIdx.y * 128;
    const int panel = blockIdx.x;
    const int which = panel >> 3, h = panel & 7;
    f32x4 acc[4][4] = {};
    mfma_gemm_128(xb + (size_t)m0 * 1024, 1024,
                  Wtb + (size_t)panel * 128 * 1024, 1024, 1024, As, Bs, acc);
    const int tid = threadIdx.x, wave = tid >> 6, lane = tid & 63;
    const int lrow = lane & 15, lquad = lane >> 4;
    const int wm = (wave >> 1) * 64, wn = (wave & 1) * 64;
    if (which == 1) {
        #pragma unroll
        for (int i = 0; i < 4; ++i) {
            int mb = m0 + wm + i * 16 + lquad * 4;    // r=0 row; r=0..3 consecutive
            int bb = mb >> 12, sb = mb & 4095;
            int bh = bb * 8 + h;
            size_t vbase = ((size_t)bh * 8 + (sb >> 9)) * 128;
            #pragma unroll
            for (int j = 0; j < 4; ++j) {
                int col = wn + j * 16 + lrow;
                ushort4 o;
                o.x = f2b(acc[i][j][0]); o.y = f2b(acc[i][j][1]);
                o.z = f2b(acc[i][j][2]); o.w = f2b(acc[i][j][3]);
                *(ushort4*)(Vtb + ((vbase + col) * 512 + (sb & 511))) = o;
            }
        }
    } else {
        unsigned short* Dst = (which == 0) ? Kbb : Qbb;
        #pragma unroll
        for (int i = 0; i < 4; ++i)
            #pragma unroll
            for (int r = 0; r < 4; ++r) {
                int m = m0 + wm + i * 16 + lquad * 4 + r;
                int bb = m >> 12, s = m & 4095;
                int bh = bb * 8 + h;
                size_t rowbase = ((size_t)bh * 4096 + s) * 128;
                #pragma unroll
                for (int j = 0; j < 4; ++j)
                    Dst[rowbase + wn + j * 16 + lrow] = f2b(acc[i][j][r]);
            }
    }
}

// ---------------------------------------------------------------------------
// Output projection: Attb (8192x1024 bf16) @ Woutb (1024x1024 bf16 = Wout^T)
// GRID TRANSPOSED: n-tile on x (8), m-tile on y (64); 8 % 8 == 0 -> each
// B column-panel stays on one XCD.
// ---------------------------------------------------------------------------
__global__ __launch_bounds__(256) void gemm_out_mfma(
    const unsigned short* __restrict__ A, const unsigned short* __restrict__ Bt,
    float* __restrict__ C)
{
    __shared__ unsigned short As[3 * 128 * 32];
    __shared__ unsigned short Bs[3 * 128 * 32];
    const int m0 = blockIdx.y * 128, n0 = blockIdx.x * 128;
    f32x4 acc[4][4] = {};
    mfma_gemm_128(A + (size_t)m0 * 1024, 1024,
                  Bt + (size_t)n0 * 1024, 1024, 1024, As, Bs, acc);
    const int tid = threadIdx.x, wave = tid >> 6, lane = tid & 63;
    const int lrow = lane & 15, lquad = lane >> 4;
    const int wm = (wave >> 1) * 64, wn = (wave & 1) * 64;
    #pragma unroll
    for (int i = 0; i < 4; ++i)
        #pragma unroll
        for (int r = 0; r < 4; ++r) {
            int m = m0 + wm + i * 16 + lquad * 4 + r;
            #pragma unroll
            for (int j = 0; j < 4; ++j)
                C[(size_t)m * 1024 + n0 + wn + j * 16 + lrow] = acc[i][j][r];
        }
}

// ---------------------------------------------------------------------------
// ac_gemm SPLIT: even blocks E = -(SkT @ SkTs^T-layout), odd blocks
// C = SkT @ Vt. grid 256 -> 1 block/CU. Proven 3-buffer 2-deep core.
// ---------------------------------------------------------------------------
__global__ __launch_bounds__(256) void ac_gemm(
    const unsigned short* __restrict__ SkT, const unsigned short* __restrict__ SkTs,
    const unsigned short* __restrict__ Vtb,
    unsigned short* __restrict__ Emat, float* __restrict__ Cmat)
{
    __shared__ unsigned short As[3 * 128 * 32];
    __shared__ unsigned short Bs[3 * 128 * 32];
    const int pair = blockIdx.x >> 1, which = blockIdx.x & 1;   // block-uniform
    const int bh = pair >> 3, seg = pair & 7;
    const unsigned short* Ap = SkT + (size_t)bh * 128 * 4096 + seg * 512;
    const unsigned short* Bp = which
        ? (Vtb  + (size_t)pair * 128 * 512)
        : (SkTs + (size_t)bh * 128 * 4096 + seg * 512);
    const int ldb = which ? 512 : 4096;
    f32x4 acc[4][4] = {};
    mfma_gemm_128(Ap, 4096, Bp, ldb, 512, As, Bs, acc);
    const int tid = threadIdx.x, wave = tid >> 6, lane = tid & 63;
    const int lrow = lane & 15, lquad = lane >> 4;
    const int wm = (wave >> 1) * 64, wn = (wave & 1) * 64;
    if (which == 0) {
        #pragma unroll
        for (int i = 0; i < 4; ++i)
            #pragma unroll
            for (int r = 0; r < 4; ++r) {
                int m = wm + i * 16 + lquad * 4 + r;
                #pragma unroll
                for (int j = 0; j < 4; ++j)
                    Emat[(size_t)pair * 16384 + (size_t)m * 128 + wn + j * 16 + lrow]
                        = f2b(-acc[i][j][r]);
            }
    } else {
        #pragma unroll
        for (int i = 0; i < 4; ++i)
            #pragma unroll
            for (int r = 0; r < 4; ++r) {
                int m = wm + i * 16 + lquad * 4 + r;
                #pragma unroll
                for (int j = 0; j < 4; ++j)
                    Cmat[(size_t)pair * 16384 + (size_t)m * 128 + wn + j * 16 + lrow]
                        = acc[i][j][r];
            }
    }
}

// ---------------------------------------------------------------------------
// Sequential scan: per bh, mem (128x128) lives in registers across 8 steps.
// mem_{i+1} = mem_i + E_i@mem_i + C_i. Snapshots Memb[bh][i] (bf16, [dv][dk]).
// ---------------------------------------------------------------------------
__global__ __launch_bounds__(512) void scan_step(
    const unsigned short* __restrict__ Emat, const float* __restrict__ Cmat,
    unsigned short* __restrict__ Memb)
{
    __shared__ unsigned short msh[128][136];   // memT shadow [v][k], padded
    const int t = threadIdx.x;
    const int wv = t >> 6, lane = t & 63;
    const int n16 = lane & 15, quad = lane >> 4;
    const int bh = blockIdx.x;
    f32x4 macc[8] = {};    // mem[k' = wv*16+quad*4+r][v = vt*16+n16]
    for (int seg = 0; seg < 8; ++seg) {
        unsigned short* gm = Memb + ((size_t)(bh * 8 + seg)) * 16384;
        #pragma unroll
        for (int vt = 0; vt < 8; ++vt) {
            ushort4 o;
            o.x = f2b(macc[vt][0]); o.y = f2b(macc[vt][1]);
            o.z = f2b(macc[vt][2]); o.w = f2b(macc[vt][3]);
            *(ushort4*)&msh[vt * 16 + n16][wv * 16 + quad * 4] = o;
            *(ushort4*)(gm + (size_t)(vt * 16 + n16) * 128 + wv * 16 + quad * 4) = o;
        }
        if (seg == 7) break;
        __syncthreads();
        const unsigned short* Ep = Emat + ((size_t)(bh * 8 + seg)) * 16384
                                 + (size_t)(wv * 16 + n16) * 128;
        bf16x8 ea[4];
        #pragma unroll
        for (int kf = 0; kf < 4; ++kf)
            ea[kf] = *(const bf16x8*)(Ep + kf * 32 + quad * 8);
        const float* Cp = Cmat + ((size_t)(bh * 8 + seg)) * 16384
                        + (size_t)(wv * 16 + quad * 4) * 128;
        #pragma unroll
        for (int vt = 0; vt < 8; ++vt)
            #pragma unroll
            for (int r = 0; r < 4; ++r)
                macc[vt][r] += Cp[(size_t)r * 128 + vt * 16 + n16];
        #pragma unroll
        for (int vt = 0; vt < 8; ++vt)
            #pragma unroll
            for (int kf = 0; kf < 4; ++kf) {
                bf16x8 bfr = *(const bf16x8*)&msh[vt * 16 + n16][kf * 32 + quad * 8];
                macc[vt] = __builtin_amdgcn_mfma_f32_16x16x32_bf16(ea[kf], bfr, macc[vt], 0, 0, 0);
            }
        __syncthreads();
    }
}

// ---------------------------------------------------------------------------
// Flash attention + memory-attention apply, writes final bf16 Attb.
// out = gate*(sigma_q@mem_seg)/(sigma_q.z_seg) + (1-gate)*softmax(QK^T)V
//
// 32-ROW WAVES (2 strips of the SAME qt per wave) + fixed-shift softmax in
// exp2 form. Wave-private P tile -> no barriers. Balance: waves {0,1} ->
// qt=a, waves {2,3} -> qt=7-a; grid y = 4.
// ---------------------------------------------------------------------------
__global__ __launch_bounds__(256) void attn_out(
    const unsigned short* __restrict__ Qbb, const unsigned short* __restrict__ Kbb,
    const unsigned short* __restrict__ Vtb, const unsigned short* __restrict__ Memb,
    const float* __restrict__ zseg, const float* __restrict__ betas,
    unsigned short* __restrict__ Attb)
{
    __shared__ unsigned short Pl[4][32][72];   // per-wave 32-row P tile, padded
    const int tid = threadIdx.x, wave = tid >> 6, lane = tid & 63;
    const int n = lane & 15, quad = lane >> 4;
    const int bh = blockIdx.x >> 3, seg = blockIdx.x & 7;
    const int a = blockIdx.y;
    const int qt = (wave < 2) ? a : 7 - a;
    const int sp = (wave & 1) * 2;             // first strip index (0 or 2)
    const int b = bh >> 3, h = bh & 7;
    const float scale2 = 0.12751744979f;       // scale * log2(e)
    const float FSH2 = 23.083120654f;          // 16 * log2(e)

    const unsigned short* Qp = Qbb + ((size_t)bh * 4096 + seg * 512 + qt * 64 + sp * 16) * 128;
    const unsigned short* Kp = Kbb + ((size_t)bh * 4096 + seg * 512) * 128;
    const unsigned short* Vp = Vtb + ((size_t)bh * 8 + seg) * 128 * 512;

    bf16x8 aQ[2][4];
    #pragma unroll
    for (int s = 0; s < 2; ++s)
        #pragma unroll
        for (int kc = 0; kc < 4; ++kc)
            aQ[s][kc] = *(const bf16x8*)(Qp + (size_t)(s * 16 + n) * 128 + kc * 32 + quad * 8);

    f32x4 O[2][8] = {};
    float lpart[2][4] = {};

    for (int jt = 0; jt <= qt; ++jt) {
        f32x4 Sf[2][4] = {};
        #pragma unroll
        for (int kc = 0; kc < 4; ++kc) {
            bf16x8 bK[4];
            #pragma unroll
            for (int ns = 0; ns < 4; ++ns)
                bK[ns] = *(const bf16x8*)(Kp + (size_t)(jt * 64 + ns * 16 + n) * 128 + kc * 32 + quad * 8);
            #pragma unroll
            for (int ns = 0; ns < 4; ++ns) {
                Sf[0][ns] = __builtin_amdgcn_mfma_f32_16x16x32_bf16(aQ[0][kc], bK[ns], Sf[0][ns], 0, 0, 0);
                Sf[1][ns] = __builtin_amdgcn_mfma_f32_16x16x32_bf16(aQ[1][kc], bK[ns], Sf[1][ns], 0, 0, 0);
            }
        }
        const bool diag = (jt == qt);
        #pragma unroll
        for (int s = 0; s < 2; ++s)
            #pragma unroll
            for (int reg = 0; reg < 4; ++reg) {
                #pragma unroll
                for (int ns = 0; ns < 4; ++ns) {
                    float sv = Sf[s][ns][reg] * scale2 - FSH2;
                    if (diag) {
                        int grow = qt * 64 + (sp + s) * 16 + quad * 4 + reg;
                        int gcol = jt * 64 + ns * 16 + n;
                        if (gcol > grow) sv = -1e30f;
                    }
                    float p = exp2f(sv);
                    lpart[s][reg] += p;
                    Pl[wave][s * 16 + quad * 4 + reg][ns * 16 + n] = f2b(p);
                }
            }
        // wave-private LDS: lgkmcnt ordering only, no barrier.
        bf16x8 aP[2][2];
        #pragma unroll
        for (int s = 0; s < 2; ++s) {
            aP[s][0] = *(const bf16x8*)&Pl[wave][s * 16 + n][quad * 8];
            aP[s][1] = *(const bf16x8*)&Pl[wave][s * 16 + n][32 + quad * 8];
        }
        #pragma unroll
        for (int dvs = 0; dvs < 8; ++dvs) {
            bf16x8 bV0 = *(const bf16x8*)(Vp + (size_t)(dvs * 16 + n) * 512 + jt * 64 + quad * 8);
            bf16x8 bV1 = *(const bf16x8*)(Vp + (size_t)(dvs * 16 + n) * 512 + jt * 64 + 32 + quad * 8);
            O[0][dvs] = __builtin_amdgcn_mfma_f32_16x16x32_bf16(aP[0][0], bV0, O[0][dvs], 0, 0, 0);
            O[0][dvs] = __builtin_amdgcn_mfma_f32_16x16x32_bf16(aP[0][1], bV1, O[0][dvs], 0, 0, 0);
            O[1][dvs] = __builtin_amdgcn_mfma_f32_16x16x32_bf16(aP[1][0], bV0, O[1][dvs], 0, 0, 0);
            O[1][dvs] = __builtin_amdgcn_mfma_f32_16x16x32_bf16(aP[1][1], bV1, O[1][dvs], 0, 0, 0);
        }
    }
    // ---- epilogue per strip (sequential to bound register pressure)
    const float* zp = zseg + (size_t)(bh * 8 + seg) * 128;
    const unsigned short* Mp = Memb + (size_t)(bh * 8 + seg) * 16384;
    #pragma unroll
    for (int s = 0; s < 2; ++s) {
        float l_i[4];
        #pragma unroll
        for (int r = 0; r < 4; ++r) {
            float rs = lpart[s][r];
            rs += __shfl_xor(rs, 1);
            rs += __shfl_xor(rs, 2);
            rs += __shfl_xor(rs, 4);
            rs += __shfl_xor(rs, 8);
            l_i[r] = rs;
        }
        float den = 0.f;
        bf16x8 aS[4];
        #pragma unroll
        for (int kc = 0; kc < 4; ++kc) {
            float4 z0 = *(const float4*)(zp + kc * 32 + quad * 8);
            float4 z1 = *(const float4*)(zp + kc * 32 + quad * 8 + 4);
            float zv[8] = {z0.x, z0.y, z0.z, z0.w, z1.x, z1.y, z1.z, z1.w};
            bf16x8 aa;
            #pragma unroll
            for (int j = 0; j < 8; ++j) {
                float sv = elu1(b2f((unsigned short)aQ[s][kc][j]));
                den += sv * zv[j];
                aa[j] = (short)f2b(sv);
            }
            aS[kc] = aa;
        }
        den += __shfl_xor(den, 16);
        den += __shfl_xor(den, 32);
        f32x4 Om[8] = {};
        #pragma unroll
        for (int dvs = 0; dvs < 8; ++dvs)
            #pragma unroll
            for (int kc = 0; kc < 4; ++kc) {
                bf16x8 bm = *(const bf16x8*)(Mp + (size_t)(dvs * 16 + n) * 128 + kc * 32 + quad * 8);
                Om[dvs] = __builtin_amdgcn_mfma_f32_16x16x32_bf16(aS[kc], bm, Om[dvs], 0, 0, 0);
            }
        float irm[4], inv[4];
        #pragma unroll
        for (int r = 0; r < 4; ++r) {
            irm[r] = 1.f / __shfl(den, quad * 4 + r);
            inv[r] = 1.f / l_i[r];
        }
        #pragma unroll
        for (int dvs = 0; dvs < 8; ++dvs) {
            int dv = dvs * 16 + n;
            float g = sigmoidf(betas[h * 128 + dv]);
            #pragma unroll
            for (int r = 0; r < 4; ++r) {
                int srow = seg * 512 + qt * 64 + (sp + s) * 16 + quad * 4 + r;
                float val = g * Om[dvs][r] * irm[r] + (1.f - g) * O[s][dvs][r] * inv[r];
                Attb[((size_t)b * 4096 + srow) * 1024 + h * 128 + dv] = f2b(val);
            }
        }
    }
}

extern "C" void kernel_launch(void* const* d_in, const int* in_sizes, int n_in,
                              void* d_out, int out_size, void* d_ws, size_t ws_size,
                              hipStream_t stream) {
    const float* x     = (const float*)d_in[0];
    const float* Wk    = (const float*)d_in[1];
    const float* Wv    = (const float*)d_in[2];
    const float* Wq    = (const float*)d_in[3];
    const float* Wout  = (const float*)d_in[4];
    const float* betas = (const float*)d_in[5];
    float* out = (float*)d_out;

    // workspace (~97 MB)
    unsigned short* Qbb  = (unsigned short*)d_ws;           // 16MB (BH,S,128)
    unsigned short* Kbb  = Qbb + 8388608;                   // 16MB
    unsigned short* Vtb  = Kbb + 8388608;                   // 16MB (BH,8,128dv,512s)
    unsigned short* SkT  = Vtb + 8388608;                   // 16MB (BH,128dk,4096s)
    unsigned short* SkTs = SkT + 8388608;                   // 16MB
    unsigned short* Emat = SkTs + 8388608;                  // 4MB  (BH*8,128,128)
    unsigned short* Memb = Emat + 2097152;                  // 4MB  (BH*8,128dv,128dk)
    float* Cmat   = (float*)(Memb + 2097152);               // 8MB  (BH*8,128,128)
    float* colsum = Cmat + 2097152;                         // 64KB (BH*8,128)
    float* zseg   = colsum + 16384;                         // 64KB
    float* den    = zseg + 16384;                           // 256KB (BH,4096)
    // aliases into dead regions:
    unsigned short* xb    = SkT;      // consumed by gemm_qkv before sigma_kT2 writes SkT
    unsigned short* Wtb   = SkTs;     // consumed by gemm_qkv
    unsigned short* Attb  = SkT;      // SkT dead after ac_gemm
    unsigned short* Woutb = SkTs;     // SkTs dead after ac_gemm

    conv_bf16<<<8192, 256, 0, stream>>>(x, xb);
    transpose_conv3<<<dim3(4, 32, 24), 256, 0, stream>>>(Wk, Wv, Wq, Wtb);
    gemm_qkv_mfma<<<dim3(24, 64), 256, 0, stream>>>(xb, Wtb, Qbb, Kbb, Vtb);
    colsum_k<<<128, 256, 0, stream>>>(Kbb, colsum);
    den_z<<<128, 256, 0, stream>>>(Kbb, colsum, den, zseg);
    sigma_kT2<<<dim3(128, 4, 16), 256, 0, stream>>>(Kbb, den, SkT, SkTs);
    ac_gemm<<<256, 256, 0, stream>>>(SkT, SkTs, Vtb, Emat, Cmat);
    scan_step<<<16, 512, 0, stream>>>(Emat, Cmat, Memb);
    attn_out<<<dim3(128, 4), 256, 0, stream>>>(Qbb, Kbb, Vtb, Memb, zseg, betas, Attb);
    transpose_conv<<<dim3(32, 32, 1), 256, 0, stream>>>(Wout, Woutb, 1024, 1024);
    gemm_out_mfma<<<dim3(8, 64), 256, 0, stream>>>(Attb, Woutb, out);
}

// Round 16
// 353.014 us; speedup vs baseline: 1.0116x; 1.0116x over previous
//
#include <hip/hip_runtime.h>

// Problem constants
#define B_  2
#define S_  4096
#define D_  1024
#define H_  8
#define DK_ 128
#define DV_ 128
#define SEG_ 512
#define NSEG_ 8
#define BH_ 16
#define M_ 8192          // B*S

typedef __attribute__((ext_vector_type(8))) short bf16x8;
typedef __attribute__((ext_vector_type(4))) float f32x4;

__device__ __forceinline__ float elu1(float x) { return x > 0.f ? x + 1.f : __expf(x); }
__device__ __forceinline__ float sigmoidf(float x) { return 1.f / (1.f + __expf(-x)); }

__device__ __forceinline__ unsigned short f2b(float f) {  // RNE fp32->bf16
    union { float f; unsigned int u; } x; x.f = f;
    unsigned int r = x.u + 0x7fffu + ((x.u >> 16) & 1u);
    return (unsigned short)(r >> 16);
}
__device__ __forceinline__ float b2f(unsigned short u) {
    union { unsigned int u; float f; } x; x.u = ((unsigned int)u) << 16; return x.f;
}

__device__ __forceinline__ void gl2lds16(const void* g, void* l) {
    __builtin_amdgcn_global_load_lds(
        (const __attribute__((address_space(1))) void*)g,
        (__attribute__((address_space(3))) void*)l, 16, 0, 0);
}

// ---------------------------------------------------------------------------
// fp32 -> bf16 row-major convert
// ---------------------------------------------------------------------------
__global__ __launch_bounds__(256) void conv_bf16(
    const float* __restrict__ src, unsigned short* __restrict__ dst)
{
    int i = (blockIdx.x * 256 + threadIdx.x) * 4;
    float4 v = *(const float4*)(src + i);
    ushort4 o;
    o.x = f2b(v.x); o.y = f2b(v.y); o.z = f2b(v.z); o.w = f2b(v.w);
    *(ushort4*)(dst + i) = o;
}

// ---------------------------------------------------------------------------
// fp32 (R x C) -> bf16 transposed (C x R). blockIdx.z = matrix index.
// ---------------------------------------------------------------------------
__global__ __launch_bounds__(256) void transpose_conv(
    const float* __restrict__ src, unsigned short* __restrict__ dst, int R, int C)
{
    __shared__ float tile[32][33];
    const size_t moff = (size_t)blockIdx.z * R * C;
    src += moff; dst += moff;
    const int c0 = blockIdx.x * 32, r0 = blockIdx.y * 32;
    const int tx = threadIdx.x & 31, ty = threadIdx.x >> 5;   // 32 x 8
    #pragma unroll
    for (int i = 0; i < 32; i += 8)
        tile[ty + i][tx] = src[(size_t)(r0 + ty + i) * C + c0 + tx];
    __syncthreads();
    #pragma unroll
    for (int i = 0; i < 32; i += 8)
        dst[(size_t)(c0 + ty + i) * R + r0 + tx] = f2b(tile[tx][ty + i]);
}

// ---------------------------------------------------------------------------
// Fused Wk/Wv/Wq transpose: 24 matrices (1024x128 each) in one launch.
// ---------------------------------------------------------------------------
__global__ __launch_bounds__(256) void transpose_conv3(
    const float* __restrict__ Wk, const float* __restrict__ Wv,
    const float* __restrict__ Wq, unsigned short* __restrict__ dst)
{
    __shared__ float tile[32][33];
    const int z = blockIdx.z;
    const int w = z >> 3;
    const float* src = (w == 0) ? Wk : (w == 1) ? Wv : Wq;
    src += (size_t)(z & 7) * 131072;
    dst += (size_t)z * 131072;
    const int c0 = blockIdx.x * 32, r0 = blockIdx.y * 32;
    const int tx = threadIdx.x & 31, ty = threadIdx.x >> 5;   // 32 x 8
    #pragma unroll
    for (int i = 0; i < 32; i += 8)
        tile[ty + i][tx] = src[(size_t)(r0 + ty + i) * 128 + c0 + tx];
    __syncthreads();
    #pragma unroll
    for (int i = 0; i < 32; i += 8)
        dst[(size_t)(c0 + ty + i) * 1024 + r0 + tx] = f2b(tile[tx][ty + i]);
}

// ---------------------------------------------------------------------------
// colsum[bh*8+seg][dk] = sum_{s in seg} elu1(K[s][dk])
// ---------------------------------------------------------------------------
__global__ __launch_bounds__(256) void colsum_k(
    const unsigned short* __restrict__ Kbb, float* __restrict__ colsum)
{
    __shared__ float red[32][128];
    const int t = threadIdx.x;
    const int bh = blockIdx.x >> 3, seg = blockIdx.x & 7;
    const unsigned short* Kp = Kbb + ((size_t)bh * 4096 + seg * 512) * 128;
    const int rbase = t >> 3, c0 = (t & 7) * 16;
    float part[16] = {};
    for (int chunk = 0; chunk < 16; ++chunk) {
        const unsigned short* p = Kp + (size_t)(chunk * 32 + rbase) * 128 + c0;
        bf16x8 a = *(const bf16x8*)p;
        bf16x8 b = *(const bf16x8*)(p + 8);
        #pragma unroll
        for (int j = 0; j < 8; ++j) {
            part[j]     += elu1(b2f((unsigned short)a[j]));
            part[j + 8] += elu1(b2f((unsigned short)b[j]));
        }
    }
    #pragma unroll
    for (int j = 0; j < 16; ++j) red[rbase][c0 + j] = part[j];
    __syncthreads();
    if (t < 128) {
        float s = 0.f;
        #pragma unroll
        for (int r = 0; r < 32; ++r) s += red[r][t];
        colsum[(size_t)blockIdx.x * 128 + t] = s;
    }
}

// ---------------------------------------------------------------------------
// zseg[bh*8+seg][dk] = 1/128 + prefix(colsum); den[bh][s] = sigma_k[s].zseg
// ---------------------------------------------------------------------------
__global__ __launch_bounds__(256) void den_z(
    const unsigned short* __restrict__ Kbb, const float* __restrict__ colsum,
    float* __restrict__ den, float* __restrict__ zseg)
{
    __shared__ float zs[128];
    const int t = threadIdx.x;
    const int bh = blockIdx.x >> 3, seg = blockIdx.x & 7;
    if (t < 128) {
        float z = 1.f / 128.f;
        for (int j = 0; j < seg; ++j) z += colsum[(size_t)(bh * 8 + j) * 128 + t];
        zs[t] = z;
        zseg[(size_t)blockIdx.x * 128 + t] = z;
    }
    __syncthreads();
    #pragma unroll
    for (int rr = 0; rr < 2; ++rr) {
        int s = t + rr * 256;
        const unsigned short* kp = Kbb + ((size_t)bh * 4096 + seg * 512 + s) * 128;
        float d = 0.f;
        #pragma unroll 4
        for (int f = 0; f < 16; ++f) {
            bf16x8 a = *(const bf16x8*)(kp + f * 8);
            #pragma unroll
            for (int j = 0; j < 8; ++j)
                d += elu1(b2f((unsigned short)a[j])) * zs[f * 8 + j];
        }
        den[(size_t)bh * 4096 + seg * 512 + s] = d;
    }
}

// ---------------------------------------------------------------------------
// SkT[bh][dk][s] = elu1(K[s][dk]); SkTs = SkT / den[s]
// ---------------------------------------------------------------------------
__global__ __launch_bounds__(256) void sigma_kT2(
    const unsigned short* __restrict__ Kbb, const float* __restrict__ den,
    unsigned short* __restrict__ SkT, unsigned short* __restrict__ SkTs)
{
    __shared__ float tile[32][33];
    __shared__ float rden[32];
    const int bh = blockIdx.z;
    const int s0 = blockIdx.x * 32, dk0 = blockIdx.y * 32;
    const int tx = threadIdx.x & 31, ty = threadIdx.x >> 5;   // 32 x 8
    if (threadIdx.x < 32) rden[threadIdx.x] = 1.f / den[(size_t)bh * 4096 + s0 + threadIdx.x];
    #pragma unroll
    for (int i = 0; i < 32; i += 8)
        tile[ty + i][tx] = elu1(b2f(Kbb[((size_t)bh * 4096 + s0 + ty + i) * 128 + dk0 + tx]));
    __syncthreads();
    #pragma unroll
    for (int i = 0; i < 32; i += 8) {
        float v = tile[tx][ty + i];
        size_t o = ((size_t)bh * 128 + dk0 + ty + i) * 4096 + s0 + tx;
        SkT[o]  = f2b(v);
        SkTs[o] = f2b(v * rden[tx]);
    }
}

// ---------------------------------------------------------------------------
// 128x128 bf16 MFMA core (4 waves), 3-buffer 2-deep counted-vmcnt (proven).
// Session-verified schedule: STAGE(t+2) -> s_waitcnt vmcnt(8) -> s_barrier
// -> ds_read+MFMA -> s_barrier. Never drains vmcnt(0) in the main loop.
// NEXT-SESSION leads: 256^2 8-phase template (guide §5.5 T3+T4+T2+T5) for
// the GEMMs; swapped-QK^T lane-local softmax (T12) for attn_out.
// ---------------------------------------------------------------------------
__device__ __forceinline__ void mfma_gemm_128(
    const unsigned short* __restrict__ A, int lda,
    const unsigned short* __restrict__ Bt, int ldb, int K,
    unsigned short* As, unsigned short* Bs, f32x4 acc[4][4])
{
    const int tid = threadIdx.x;
    const int wave = tid >> 6, lane = tid & 63;
    const int r4 = lane >> 2;
    const int c4s = (((lane & 3) ^ ((lane >> 2) & 3)) * 8);   // swizzled source chunk
    const int lrow = lane & 15, lquad = lane >> 4;
    const int sl8 = (lquad ^ (lrow & 3)) * 8;                 // matching read slot
    const int wm = (wave >> 1) * 64, wn = (wave & 1) * 64;
    const int ar0 = wave * 32, ar1 = wave * 32 + 16;
    const int T = K >> 5;

    auto STAGE = [&](int t, int bufidx) {
        unsigned short* Ab = As + bufidx * 4096;
        unsigned short* Bb = Bs + bufidx * 4096;
        const int kk = t * 32;
        gl2lds16(A  + (size_t)(ar0 + r4) * lda + kk + c4s, Ab + ar0 * 32);
        gl2lds16(A  + (size_t)(ar1 + r4) * lda + kk + c4s, Ab + ar1 * 32);
        gl2lds16(Bt + (size_t)(ar0 + r4) * ldb + kk + c4s, Bb + ar0 * 32);
        gl2lds16(Bt + (size_t)(ar1 + r4) * ldb + kk + c4s, Bb + ar1 * 32);
    };

    STAGE(0, 0);
    STAGE(1, 1);
    int cur = 0;
    for (int t = 0; t < T; ++t) {
        if (t + 2 < T) {
            int nb = cur + 2; if (nb >= 3) nb -= 3;
            STAGE(t + 2, nb);
            asm volatile("s_waitcnt vmcnt(8)" ::: "memory");   // tile t landed
        } else if (t + 1 < T) {
            asm volatile("s_waitcnt vmcnt(4)" ::: "memory");
        } else {
            asm volatile("s_waitcnt vmcnt(0)" ::: "memory");
        }
        __builtin_amdgcn_s_barrier();
        __builtin_amdgcn_sched_barrier(0);
        const unsigned short* Ac = As + cur * 4096;
        const unsigned short* Bc = Bs + cur * 4096;
        bf16x8 af[4], bfr[4];
        #pragma unroll
        for (int i = 0; i < 4; ++i)
            af[i] = *(const bf16x8*)(Ac + (wm + i * 16 + lrow) * 32 + sl8);
        #pragma unroll
        for (int j = 0; j < 4; ++j)
            bfr[j] = *(const bf16x8*)(Bc + (wn + j * 16 + lrow) * 32 + sl8);
        #pragma unroll
        for (int i = 0; i < 4; ++i)
            #pragma unroll
            for (int j = 0; j < 4; ++j)
                acc[i][j] = __builtin_amdgcn_mfma_f32_16x16x32_bf16(af[i], bfr[j], acc[i][j], 0, 0, 0);
        __builtin_amdgcn_s_barrier();
        __builtin_amdgcn_sched_barrier(0);
        cur += 1; if (cur >= 3) cur -= 3;
    }
}

// ---------------------------------------------------------------------------
// QKV projection: xb (8192x1024 bf16) @ Wtb[panel] (128x1024 bf16 = W^T)
// Outputs: Qbb/Kbb (BH,S,128) row-major; V only as Vtb (BH,8,128dv,512s).
// V epilogue: r=0..3 land at consecutive s within one 512-block -> ushort4.
// Grid (m=64, panel=24): XCD = m%8 keeps each A-tile in ONE L2 (measured
// better than panel-major, which re-fetched A into all 8 XCDs: round 15).
// ---------------------------------------------------------------------------
__global__ __launch_bounds__(256) void gemm_qkv_mfma(
    const unsigned short* __restrict__ xb, const unsigned short* __restrict__ Wtb,
    unsigned short* __restrict__ Qbb, unsigned short* __restrict__ Kbb,
    unsigned short* __restrict__ Vtb)
{
    __shared__ unsigned short As[3 * 128 * 32];
    __shared__ unsigned short Bs[3 * 128 * 32];
    const int m0 = blockIdx.x * 128;
    const int panel = blockIdx.y;
    const int which = panel >> 3, h = panel & 7;
    f32x4 acc[4][4] = {};
    mfma_gemm_128(xb + (size_t)m0 * 1024, 1024,
                  Wtb + (size_t)panel * 128 * 1024, 1024, 1024, As, Bs, acc);
    const int tid = threadIdx.x, wave = tid >> 6, lane = tid & 63;
    const int lrow = lane & 15, lquad = lane >> 4;
    const int wm = (wave >> 1) * 64, wn = (wave & 1) * 64;
    if (which == 1) {
        #pragma unroll
        for (int i = 0; i < 4; ++i) {
            int mb = m0 + wm + i * 16 + lquad * 4;    // r=0 row; r=0..3 consecutive
            int bb = mb >> 12, sb = mb & 4095;
            int bh = bb * 8 + h;
            size_t vbase = ((size_t)bh * 8 + (sb >> 9)) * 128;
            #pragma unroll
            for (int j = 0; j < 4; ++j) {
                int col = wn + j * 16 + lrow;
                ushort4 o;
                o.x = f2b(acc[i][j][0]); o.y = f2b(acc[i][j][1]);
                o.z = f2b(acc[i][j][2]); o.w = f2b(acc[i][j][3]);
                *(ushort4*)(Vtb + ((vbase + col) * 512 + (sb & 511))) = o;
            }
        }
    } else {
        unsigned short* Dst = (which == 0) ? Kbb : Qbb;
        #pragma unroll
        for (int i = 0; i < 4; ++i)
            #pragma unroll
            for (int r = 0; r < 4; ++r) {
                int m = m0 + wm + i * 16 + lquad * 4 + r;
                int bb = m >> 12, s = m & 4095;
                int bh = bb * 8 + h;
                size_t rowbase = ((size_t)bh * 4096 + s) * 128;
                #pragma unroll
                for (int j = 0; j < 4; ++j)
                    Dst[rowbase + wn + j * 16 + lrow] = f2b(acc[i][j][r]);
            }
    }
}

// ---------------------------------------------------------------------------
// Output projection: Attb (8192x1024 bf16) @ Woutb (1024x1024 bf16 = Wout^T)
// ---------------------------------------------------------------------------
__global__ __launch_bounds__(256) void gemm_out_mfma(
    const unsigned short* __restrict__ A, const unsigned short* __restrict__ Bt,
    float* __restrict__ C)
{
    __shared__ unsigned short As[3 * 128 * 32];
    __shared__ unsigned short Bs[3 * 128 * 32];
    const int m0 = blockIdx.x * 128, n0 = blockIdx.y * 128;
    f32x4 acc[4][4] = {};
    mfma_gemm_128(A + (size_t)m0 * 1024, 1024,
                  Bt + (size_t)n0 * 1024, 1024, 1024, As, Bs, acc);
    const int tid = threadIdx.x, wave = tid >> 6, lane = tid & 63;
    const int lrow = lane & 15, lquad = lane >> 4;
    const int wm = (wave >> 1) * 64, wn = (wave & 1) * 64;
    #pragma unroll
    for (int i = 0; i < 4; ++i)
        #pragma unroll
        for (int r = 0; r < 4; ++r) {
            int m = m0 + wm + i * 16 + lquad * 4 + r;
            #pragma unroll
            for (int j = 0; j < 4; ++j)
                C[(size_t)m * 1024 + n0 + wn + j * 16 + lrow] = acc[i][j][r];
        }
}

// ---------------------------------------------------------------------------
// ac_gemm SPLIT: E and C are independent products sharing only A, so run
// them as separate blocks (grid 256 -> 1 block/CU instead of 0.5). Each
// block is an exact instance of the proven mfma_gemm_128 counted-vmcnt core.
//   even blocks: E = -(SkT @ SkTs^T-layout)  (bf16 out)
//   odd  blocks: C =   SkT @ Vt              (fp32 out)
// ---------------------------------------------------------------------------
__global__ __launch_bounds__(256) void ac_gemm(
    const unsigned short* __restrict__ SkT, const unsigned short* __restrict__ SkTs,
    const unsigned short* __restrict__ Vtb,
    unsigned short* __restrict__ Emat, float* __restrict__ Cmat)
{
    __shared__ unsigned short As[3 * 128 * 32];
    __shared__ unsigned short Bs[3 * 128 * 32];
    const int pair = blockIdx.x >> 1, which = blockIdx.x & 1;   // block-uniform
    const int bh = pair >> 3, seg = pair & 7;
    const unsigned short* Ap = SkT + (size_t)bh * 128 * 4096 + seg * 512;
    const unsigned short* Bp = which
        ? (Vtb  + (size_t)pair * 128 * 512)
        : (SkTs + (size_t)bh * 128 * 4096 + seg * 512);
    const int ldb = which ? 512 : 4096;
    f32x4 acc[4][4] = {};
    mfma_gemm_128(Ap, 4096, Bp, ldb, 512, As, Bs, acc);
    const int tid = threadIdx.x, wave = tid >> 6, lane = tid & 63;
    const int lrow = lane & 15, lquad = lane >> 4;
    const int wm = (wave >> 1) * 64, wn = (wave & 1) * 64;
    if (which == 0) {
        #pragma unroll
        for (int i = 0; i < 4; ++i)
            #pragma unroll
            for (int r = 0; r < 4; ++r) {
                int m = wm + i * 16 + lquad * 4 + r;
                #pragma unroll
                for (int j = 0; j < 4; ++j)
                    Emat[(size_t)pair * 16384 + (size_t)m * 128 + wn + j * 16 + lrow]
                        = f2b(-acc[i][j][r]);
            }
    } else {
        #pragma unroll
        for (int i = 0; i < 4; ++i)
            #pragma unroll
            for (int r = 0; r < 4; ++r) {
                int m = wm + i * 16 + lquad * 4 + r;
                #pragma unroll
                for (int j = 0; j < 4; ++j)
                    Cmat[(size_t)pair * 16384 + (size_t)m * 128 + wn + j * 16 + lrow]
                        = acc[i][j][r];
            }
    }
}

// ---------------------------------------------------------------------------
// Sequential scan: per bh, mem (128x128) lives in registers across 8 steps.
// mem_{i+1} = mem_i + E_i@mem_i + C_i. Snapshots Memb[bh][i] (bf16, [dv][dk]).
// ---------------------------------------------------------------------------
__global__ __launch_bounds__(512) void scan_step(
    const unsigned short* __restrict__ Emat, const float* __restrict__ Cmat,
    unsigned short* __restrict__ Memb)
{
    __shared__ unsigned short msh[128][136];   // memT shadow [v][k], padded
    const int t = threadIdx.x;
    const int wv = t >> 6, lane = t & 63;
    const int n16 = lane & 15, quad = lane >> 4;
    const int bh = blockIdx.x;
    f32x4 macc[8] = {};    // mem[k' = wv*16+quad*4+r][v = vt*16+n16]
    for (int seg = 0; seg < 8; ++seg) {
        unsigned short* gm = Memb + ((size_t)(bh * 8 + seg)) * 16384;
        #pragma unroll
        for (int vt = 0; vt < 8; ++vt) {
            ushort4 o;
            o.x = f2b(macc[vt][0]); o.y = f2b(macc[vt][1]);
            o.z = f2b(macc[vt][2]); o.w = f2b(macc[vt][3]);
            *(ushort4*)&msh[vt * 16 + n16][wv * 16 + quad * 4] = o;
            *(ushort4*)(gm + (size_t)(vt * 16 + n16) * 128 + wv * 16 + quad * 4) = o;
        }
        if (seg == 7) break;
        __syncthreads();
        const unsigned short* Ep = Emat + ((size_t)(bh * 8 + seg)) * 16384
                                 + (size_t)(wv * 16 + n16) * 128;
        bf16x8 ea[4];
        #pragma unroll
        for (int kf = 0; kf < 4; ++kf)
            ea[kf] = *(const bf16x8*)(Ep + kf * 32 + quad * 8);
        const float* Cp = Cmat + ((size_t)(bh * 8 + seg)) * 16384
                        + (size_t)(wv * 16 + quad * 4) * 128;
        #pragma unroll
        for (int vt = 0; vt < 8; ++vt)
            #pragma unroll
            for (int r = 0; r < 4; ++r)
                macc[vt][r] += Cp[(size_t)r * 128 + vt * 16 + n16];
        #pragma unroll
        for (int vt = 0; vt < 8; ++vt)
            #pragma unroll
            for (int kf = 0; kf < 4; ++kf) {
                bf16x8 bfr = *(const bf16x8*)&msh[vt * 16 + n16][kf * 32 + quad * 8];
                macc[vt] = __builtin_amdgcn_mfma_f32_16x16x32_bf16(ea[kf], bfr, macc[vt], 0, 0, 0);
            }
        __syncthreads();
    }
}

// ---------------------------------------------------------------------------
// Flash attention + memory-attention apply, writes final bf16 Attb.
// out = gate*(sigma_q@mem_seg)/(sigma_q.z_seg) + (1-gate)*softmax(QK^T)V
//
// 32-ROW WAVES (2 strips of the SAME qt per wave) + fixed-shift softmax in
// exp2 form. Wave-private P tile -> no barriers. Balance: waves {0,1} ->
// qt=a, waves {2,3} -> qt=7-a; grid y = 4.
// ---------------------------------------------------------------------------
__global__ __launch_bounds__(256) void attn_out(
    const unsigned short* __restrict__ Qbb, const unsigned short* __restrict__ Kbb,
    const unsigned short* __restrict__ Vtb, const unsigned short* __restrict__ Memb,
    const float* __restrict__ zseg, const float* __restrict__ betas,
    unsigned short* __restrict__ Attb)
{
    __shared__ unsigned short Pl[4][32][72];   // per-wave 32-row P tile, padded
    const int tid = threadIdx.x, wave = tid >> 6, lane = tid & 63;
    const int n = lane & 15, quad = lane >> 4;
    const int bh = blockIdx.x >> 3, seg = blockIdx.x & 7;
    const int a = blockIdx.y;
    const int qt = (wave < 2) ? a : 7 - a;
    const int sp = (wave & 1) * 2;             // first strip index (0 or 2)
    const int b = bh >> 3, h = bh & 7;
    const float scale2 = 0.12751744979f;       // scale * log2(e)
    const float FSH2 = 23.083120654f;          // 16 * log2(e)

    const unsigned short* Qp = Qbb + ((size_t)bh * 4096 + seg * 512 + qt * 64 + sp * 16) * 128;
    const unsigned short* Kp = Kbb + ((size_t)bh * 4096 + seg * 512) * 128;
    const unsigned short* Vp = Vtb + ((size_t)bh * 8 + seg) * 128 * 512;

    bf16x8 aQ[2][4];
    #pragma unroll
    for (int s = 0; s < 2; ++s)
        #pragma unroll
        for (int kc = 0; kc < 4; ++kc)
            aQ[s][kc] = *(const bf16x8*)(Qp + (size_t)(s * 16 + n) * 128 + kc * 32 + quad * 8);

    f32x4 O[2][8] = {};
    float lpart[2][4] = {};

    for (int jt = 0; jt <= qt; ++jt) {
        f32x4 Sf[2][4] = {};
        #pragma unroll
        for (int kc = 0; kc < 4; ++kc) {
            bf16x8 bK[4];
            #pragma unroll
            for (int ns = 0; ns < 4; ++ns)
                bK[ns] = *(const bf16x8*)(Kp + (size_t)(jt * 64 + ns * 16 + n) * 128 + kc * 32 + quad * 8);
            #pragma unroll
            for (int ns = 0; ns < 4; ++ns) {
                Sf[0][ns] = __builtin_amdgcn_mfma_f32_16x16x32_bf16(aQ[0][kc], bK[ns], Sf[0][ns], 0, 0, 0);
                Sf[1][ns] = __builtin_amdgcn_mfma_f32_16x16x32_bf16(aQ[1][kc], bK[ns], Sf[1][ns], 0, 0, 0);
            }
        }
        const bool diag = (jt == qt);
        #pragma unroll
        for (int s = 0; s < 2; ++s)
            #pragma unroll
            for (int reg = 0; reg < 4; ++reg) {
                #pragma unroll
                for (int ns = 0; ns < 4; ++ns) {
                    float sv = Sf[s][ns][reg] * scale2 - FSH2;
                    if (diag) {
                        int grow = qt * 64 + (sp + s) * 16 + quad * 4 + reg;
                        int gcol = jt * 64 + ns * 16 + n;
                        if (gcol > grow) sv = -1e30f;
                    }
                    float p = exp2f(sv);
                    lpart[s][reg] += p;
                    Pl[wave][s * 16 + quad * 4 + reg][ns * 16 + n] = f2b(p);
                }
            }
        // wave-private LDS: lgkmcnt ordering only, no barrier.
        bf16x8 aP[2][2];
        #pragma unroll
        for (int s = 0; s < 2; ++s) {
            aP[s][0] = *(const bf16x8*)&Pl[wave][s * 16 + n][quad * 8];
            aP[s][1] = *(const bf16x8*)&Pl[wave][s * 16 + n][32 + quad * 8];
        }
        #pragma unroll
        for (int dvs = 0; dvs < 8; ++dvs) {
            bf16x8 bV0 = *(const bf16x8*)(Vp + (size_t)(dvs * 16 + n) * 512 + jt * 64 + quad * 8);
            bf16x8 bV1 = *(const bf16x8*)(Vp + (size_t)(dvs * 16 + n) * 512 + jt * 64 + 32 + quad * 8);
            O[0][dvs] = __builtin_amdgcn_mfma_f32_16x16x32_bf16(aP[0][0], bV0, O[0][dvs], 0, 0, 0);
            O[0][dvs] = __builtin_amdgcn_mfma_f32_16x16x32_bf16(aP[0][1], bV1, O[0][dvs], 0, 0, 0);
            O[1][dvs] = __builtin_amdgcn_mfma_f32_16x16x32_bf16(aP[1][0], bV0, O[1][dvs], 0, 0, 0);
            O[1][dvs] = __builtin_amdgcn_mfma_f32_16x16x32_bf16(aP[1][1], bV1, O[1][dvs], 0, 0, 0);
        }
    }
    // ---- epilogue per strip (sequential to bound register pressure)
    const float* zp = zseg + (size_t)(bh * 8 + seg) * 128;
    const unsigned short* Mp = Memb + (size_t)(bh * 8 + seg) * 16384;
    #pragma unroll
    for (int s = 0; s < 2; ++s) {
        float l_i[4];
        #pragma unroll
        for (int r = 0; r < 4; ++r) {
            float rs = lpart[s][r];
            rs += __shfl_xor(rs, 1);
            rs += __shfl_xor(rs, 2);
            rs += __shfl_xor(rs, 4);
            rs += __shfl_xor(rs, 8);
            l_i[r] = rs;
        }
        float den = 0.f;
        bf16x8 aS[4];
        #pragma unroll
        for (int kc = 0; kc < 4; ++kc) {
            float4 z0 = *(const float4*)(zp + kc * 32 + quad * 8);
            float4 z1 = *(const float4*)(zp + kc * 32 + quad * 8 + 4);
            float zv[8] = {z0.x, z0.y, z0.z, z0.w, z1.x, z1.y, z1.z, z1.w};
            bf16x8 aa;
            #pragma unroll
            for (int j = 0; j < 8; ++j) {
                float sv = elu1(b2f((unsigned short)aQ[s][kc][j]));
                den += sv * zv[j];
                aa[j] = (short)f2b(sv);
            }
            aS[kc] = aa;
        }
        den += __shfl_xor(den, 16);
        den += __shfl_xor(den, 32);
        f32x4 Om[8] = {};
        #pragma unroll
        for (int dvs = 0; dvs < 8; ++dvs)
            #pragma unroll
            for (int kc = 0; kc < 4; ++kc) {
                bf16x8 bm = *(const bf16x8*)(Mp + (size_t)(dvs * 16 + n) * 128 + kc * 32 + quad * 8);
                Om[dvs] = __builtin_amdgcn_mfma_f32_16x16x32_bf16(aS[kc], bm, Om[dvs], 0, 0, 0);
            }
        float irm[4], inv[4];
        #pragma unroll
        for (int r = 0; r < 4; ++r) {
            irm[r] = 1.f / __shfl(den, quad * 4 + r);
            inv[r] = 1.f / l_i[r];
        }
        #pragma unroll
        for (int dvs = 0; dvs < 8; ++dvs) {
            int dv = dvs * 16 + n;
            float g = sigmoidf(betas[h * 128 + dv]);
            #pragma unroll
            for (int r = 0; r < 4; ++r) {
                int srow = seg * 512 + qt * 64 + (sp + s) * 16 + quad * 4 + r;
                float val = g * Om[dvs][r] * irm[r] + (1.f - g) * O[s][dvs][r] * inv[r];
                Attb[((size_t)b * 4096 + srow) * 1024 + h * 128 + dv] = f2b(val);
            }
        }
    }
}

extern "C" void kernel_launch(void* const* d_in, const int* in_sizes, int n_in,
                              void* d_out, int out_size, void* d_ws, size_t ws_size,
                              hipStream_t stream) {
    const float* x     = (const float*)d_in[0];
    const float* Wk    = (const float*)d_in[1];
    const float* Wv    = (const float*)d_in[2];
    const float* Wq    = (const float*)d_in[3];
    const float* Wout  = (const float*)d_in[4];
    const float* betas = (const float*)d_in[5];
    float* out = (float*)d_out;

    // workspace (~97 MB)
    unsigned short* Qbb  = (unsigned short*)d_ws;           // 16MB (BH,S,128)
    unsigned short* Kbb  = Qbb + 8388608;                   // 16MB
    unsigned short* Vtb  = Kbb + 8388608;                   // 16MB (BH,8,128dv,512s)
    unsigned short* SkT  = Vtb + 8388608;                   // 16MB (BH,128dk,4096s)
    unsigned short* SkTs = SkT + 8388608;                   // 16MB
    unsigned short* Emat = SkTs + 8388608;                  // 4MB  (BH*8,128,128)
    unsigned short* Memb = Emat + 2097152;                  // 4MB  (BH*8,128dv,128dk)
    float* Cmat   = (float*)(Memb + 2097152);               // 8MB  (BH*8,128,128)
    float* colsum = Cmat + 2097152;                         // 64KB (BH*8,128)
    float* zseg   = colsum + 16384;                         // 64KB
    float* den    = zseg + 16384;                           // 256KB (BH,4096)
    // aliases into dead regions:
    unsigned short* xb    = SkT;      // consumed by gemm_qkv before sigma_kT2 writes SkT
    unsigned short* Wtb   = SkTs;     // consumed by gemm_qkv
    unsigned short* Attb  = SkT;      // SkT dead after ac_gemm
    unsigned short* Woutb = SkTs;     // SkTs dead after ac_gemm

    conv_bf16<<<8192, 256, 0, stream>>>(x, xb);
    transpose_conv3<<<dim3(4, 32, 24), 256, 0, stream>>>(Wk, Wv, Wq, Wtb);
    gemm_qkv_mfma<<<dim3(64, 24), 256, 0, stream>>>(xb, Wtb, Qbb, Kbb, Vtb);
    colsum_k<<<128, 256, 0, stream>>>(Kbb, colsum);
    den_z<<<128, 256, 0, stream>>>(Kbb, colsum, den, zseg);
    sigma_kT2<<<dim3(128, 4, 16), 256, 0, stream>>>(Kbb, den, SkT, SkTs);
    ac_gemm<<<256, 256, 0, stream>>>(SkT, SkTs, Vtb, Emat, Cmat);
    scan_step<<<16, 512, 0, stream>>>(Emat, Cmat, Memb);
    attn_out<<<dim3(128, 4), 256, 0, stream>>>(Qbb, Kbb, Vtb, Memb, zseg, betas, Attb);
    transpose_conv<<<dim3(32, 32, 1), 256, 0, stream>>>(Wout, Woutb, 1024, 1024);
    gemm_out_mfma<<<dim3(64, 8), 256, 0, stream>>>(Attb, Woutb, out);
}